// Round 2
// baseline (39.627 us; speedup 1.0000x reference)
//
#include <hip/hip_runtime.h>

// GMP: y[b,s] = sum_{l=0}^{9} C_l(b,s) * x[b,s-l], zero for s < 20.
// C_l = sum_{k=0}^{3} a[k, 9-l] |x[s-l]|^k
//     + sum_{m=0}^{9} sum_{k=1}^{4} b[k-1,l,m] |x[s-l-1-m]|^k
// All fp32. Input c unused by the reference.
//
// Design: NO LDS, NO barrier. Coefficient loads are uniform-address global
// loads with no preceding clobber -> compiler emits s_load (SMEM, scalar
// cache), freeing the LDS/VMEM vector pipes. x is read per-thread from
// global (coalesced, L1-resident reuse). Fully unrolled so all register
// indexing is static (no scratch).

constexpr int Kp = 4;
constexpr int Lp = 10;
constexpr int Mp = 10;
constexpr int Dp = Lp + Mp;   // 20
constexpr int BLK = 256;
constexpr int S_FIXED = 16384;

__global__ __launch_bounds__(BLK) void gmp_kernel(
    const float* __restrict__ x,   // (B, S, 2)
    const float* __restrict__ a,   // (K, L)
    const float* __restrict__ b,   // (K, L, M)
    float* __restrict__ out,       // (B, S, 2)
    int S)
{
    const int t = threadIdx.x;
    const int blocksPerRow = S / BLK;
    const int brow = blockIdx.x / blocksPerRow;
    const int s    = (blockIdx.x % blocksPerRow) * BLK + t;

    const float2* __restrict__ xrow =
        reinterpret_cast<const float2*>(x) + (size_t)brow * S;

    float2 o = make_float2(0.f, 0.f);
    if (s >= Dp) {
        // powers of |x[s-d]| for d = 0..19, all statically indexed
        float q1[Dp], q2[Dp], q3[Dp], q4[Dp];
        float re[Lp], im[Lp];
        #pragma unroll
        for (int d = 0; d < Dp; ++d) {
            const float2 v = xrow[s - d];
            const float m2 = v.x * v.x + v.y * v.y;
            const float r  = __builtin_amdgcn_sqrtf(m2);
            q1[d] = r;
            q2[d] = m2;
            q3[d] = m2 * r;
            q4[d] = m2 * m2;
            if (d < Lp) { re[d] = v.x; im[d] = v.y; }
        }

        float yr = 0.f, yi = 0.f;
        #pragma unroll
        for (int l = 0; l < Lp; ++l) {
            // a-part: sum_k a[k,9-l] * q_k  (q0 = 1)
            float C = a[0 * Lp + (Lp - 1 - l)]
                    + a[1 * Lp + (Lp - 1 - l)] * q1[l]
                    + a[2 * Lp + (Lp - 1 - l)] * q2[l]
                    + a[3 * Lp + (Lp - 1 - l)] * q3[l];
            // b-part: sum_m sum_{k=1..4} b[k-1,l,m] * q_k[l+1+m]
            #pragma unroll
            for (int m = 0; m < Mp; ++m) {
                const int d = l + 1 + m;
                const float* bp = b + l * Mp + m;       // + k*100 strides
                C += bp[0 * Lp * Mp] * q1[d]
                   + bp[1 * Lp * Mp] * q2[d]
                   + bp[2 * Lp * Mp] * q3[d]
                   + bp[3 * Lp * Mp] * q4[d];
            }
            yr += C * re[l];
            yi += C * im[l];
        }
        o.x = yr;
        o.y = yi;
    }
    reinterpret_cast<float2*>(out)[(size_t)brow * S + s] = o;
}

extern "C" void kernel_launch(void* const* d_in, const int* in_sizes, int n_in,
                              void* d_out, int out_size, void* d_ws, size_t ws_size,
                              hipStream_t stream) {
    const float* x = (const float*)d_in[0];
    const float* a = (const float*)d_in[1];
    const float* b = (const float*)d_in[2];
    // d_in[3] (c) is unused by the reference.
    float* out = (float*)d_out;

    const int S = S_FIXED;
    const int B = in_sizes[0] / (2 * S);
    const int nblocks = B * (S / BLK);

    gmp_kernel<<<dim3(nblocks), dim3(BLK), 0, stream>>>(x, a, b, out, S);
}